// Round 1
// baseline (23009.644 us; speedup 1.0000x reference)
//
#include <hip/hip_runtime.h>
#include <cstdint>
#include <cstddef>

// ---------------------------------------------------------------- sizes
#define LT 512
#define BB 128
#define DD 512
#define HH 1024
#define HD 1536
#define MT (LT*BB)   // 65536

typedef __bf16 bf16;
typedef __bf16 bf16x8 __attribute__((ext_vector_type(8)));
typedef __bf16 bf16x4 __attribute__((ext_vector_type(4)));
typedef float  f32x4  __attribute__((ext_vector_type(4)));

// ---------------------------------------------------------------- ws layout (bytes)
#define O_WZR 0u                 // bf16 [2048][1536]  rows 0..1023 = W_z, 1024.. = W_r (full H+D rows)
#define O_WHR 6291456u           // bf16 [1024][1024]  W_h[:, :H]
#define O_WXH 8388608u           // bf16 [1024][512]   W_h[:, H:]
#define O_XB  9437184u           // bf16 [65536][512]  x cast to bf16
#define O_H32 76546048u          // f32  [128][1024]   h state
#define O_HB  77070336u          // bf16 [128][1024]   h rounded
#define O_RHB 77332480u          // bf16 [128][1024]   r*h rounded
#define O_ZB  77594624u          // f32  [128][1024]   z gate
#define O_BAR 78118912u          // barrier counters
#define WS_NEED 78123008u

// ---------------------------------------------------------------- small prep kernels
__global__ void k_cvt(const float* __restrict__ s, bf16* __restrict__ d, int n8) {
  int i = blockIdx.x*256 + threadIdx.x;
  if (i >= n8) return;
  const float4* p = (const float4*)s + (size_t)i*2;
  float4 a = p[0], b = p[1];
  bf16x8 v = {(bf16)a.x,(bf16)a.y,(bf16)a.z,(bf16)a.w,(bf16)b.x,(bf16)b.y,(bf16)b.z,(bf16)b.w};
  *((bf16x8*)d + i) = v;
}

__global__ void k_split_wh(const float* __restrict__ Wh, bf16* __restrict__ whr, bf16* __restrict__ wxh) {
  int i = blockIdx.x*256 + threadIdx.x;      // 1024*192 threads, 8 elems each
  if (i >= 1024*192) return;
  int row = i / 192, c8 = (i % 192)*8;
  const float4* p = (const float4*)(Wh + (size_t)row*HD + c8);
  float4 a = p[0], b = p[1];
  bf16x8 v = {(bf16)a.x,(bf16)a.y,(bf16)a.z,(bf16)a.w,(bf16)b.x,(bf16)b.y,(bf16)b.z,(bf16)b.w};
  bf16* dptr = (c8 < HH) ? (whr + (size_t)row*HH + c8) : (wxh + (size_t)row*DD + (c8 - HH));
  *(bf16x8*)dptr = v;
}

__global__ void k_init_h(const float* __restrict__ h0, float* __restrict__ h32, bf16* __restrict__ hb) {
  int i = blockIdx.x*256 + threadIdx.x;      // 32768 threads of float4
  float4 a = ((const float4*)h0)[i];
  ((float4*)h32)[i] = a;
  bf16x4 v = {(bf16)a.x,(bf16)a.y,(bf16)a.z,(bf16)a.w};
  *((bf16x4*)hb + i) = v;
}

// ---------------------------------------------------------------- Xh GEMM: out = x @ Wxh^T + b_h
// M=65536, N=1024, K=512. 128x128 tile, BK=64, 4 waves x (64x64), st-16x32 XOR swizzle (T2).
__global__ __launch_bounds__(256) void k_gemm_xh(
    const bf16* __restrict__ xb, const bf16* __restrict__ wxh,
    const float* __restrict__ bh, float* __restrict__ out)
{
  __shared__ char As[16384];
  __shared__ char Bs[16384];
  const int bid = blockIdx.x;
  const int nt8 = bid & 7, mtb = bid >> 3;
  const int tid = threadIdx.x;
  const int lane = tid & 63, wv = tid >> 6;
  const int l15 = lane & 15, q = lane >> 4;
  const int wm = wv >> 1, wn = wv & 1;
  f32x4 acc[4][4] = {};
  const char* Ab = (const char*)(xb + (size_t)mtb*128*DD);
  const char* Bb = (const char*)(wxh + (size_t)nt8*128*DD);
  const int crow = tid >> 3, ccb = (tid & 7)*16;                 // staging coords (16B chunks)
  const int cdst = crow*128 + (ccb ^ ((crow & 7) << 4));         // swizzled LDS dest
  for (int kt = 0; kt < 8; ++kt) {
    __syncthreads();
    #pragma unroll
    for (int i = 0; i < 4; ++i) {   // linear coalesced global read, swizzled LDS write
      *(uint4*)(As + cdst + i*4096) = *(const uint4*)(Ab + (size_t)(crow + i*32)*1024 + kt*128 + ccb);
      *(uint4*)(Bs + cdst + i*4096) = *(const uint4*)(Bb + (size_t)(crow + i*32)*1024 + kt*128 + ccb);
    }
    __syncthreads();
    #pragma unroll
    for (int ks = 0; ks < 2; ++ks) {
      bf16x8 af[4], bfr[4];
      #pragma unroll
      for (int m4 = 0; m4 < 4; ++m4) {
        int row = wm*64 + m4*16 + l15, cb = ks*64 + 16*q;
        af[m4] = *(const bf16x8*)(As + row*128 + (cb ^ ((row&7)<<4)));
      }
      #pragma unroll
      for (int n4 = 0; n4 < 4; ++n4) {
        int row = wn*64 + n4*16 + l15, cb = ks*64 + 16*q;
        bfr[n4] = *(const bf16x8*)(Bs + row*128 + (cb ^ ((row&7)<<4)));
      }
      #pragma unroll
      for (int m4 = 0; m4 < 4; ++m4)
        #pragma unroll
        for (int n4 = 0; n4 < 4; ++n4)
          acc[m4][n4] = __builtin_amdgcn_mfma_f32_16x16x32_bf16(af[m4], bfr[n4], acc[m4][n4], 0, 0, 0);
    }
  }
  const int jb = nt8*128 + wn*64;
  const size_t mb = (size_t)mtb*128 + wm*64;
  #pragma unroll
  for (int n4 = 0; n4 < 4; ++n4) {
    int j = jb + n4*16 + l15;
    float bias = bh[j];
    #pragma unroll
    for (int m4 = 0; m4 < 4; ++m4)
      #pragma unroll
      for (int e = 0; e < 4; ++e) {
        size_t m = mb + m4*16 + 4*q + e;   // C/D: col = lane&15, row = 4*(lane>>4)+e
        out[m*HH + j] = acc[m4][n4][e] + bias;
      }
  }
}

// ---------------------------------------------------------------- grid barrier (2-level, sense-reversing)
__device__ __forceinline__ void grid_barrier(unsigned* bar, int bid) {
  __syncthreads();
  if (threadIdx.x == 0) {
    __threadfence();
    unsigned* leaf = bar + (bid & 15) * 32;   // 16 leaves, 128B apart
    unsigned* root = bar + 16 * 32;
    unsigned* gen  = bar + 17 * 32;
    unsigned g = __hip_atomic_load(gen, __ATOMIC_RELAXED, __HIP_MEMORY_SCOPE_AGENT);
    unsigned lold = __hip_atomic_fetch_add(leaf, 1u, __ATOMIC_ACQ_REL, __HIP_MEMORY_SCOPE_AGENT);
    if (lold == 15u) {
      __hip_atomic_store(leaf, 0u, __ATOMIC_RELAXED, __HIP_MEMORY_SCOPE_AGENT);
      unsigned rold = __hip_atomic_fetch_add(root, 1u, __ATOMIC_ACQ_REL, __HIP_MEMORY_SCOPE_AGENT);
      if (rold == 15u) {
        __hip_atomic_store(root, 0u, __ATOMIC_RELAXED, __HIP_MEMORY_SCOPE_AGENT);
        __hip_atomic_store(gen, g + 1u, __ATOMIC_RELEASE, __HIP_MEMORY_SCOPE_AGENT);
      } else {
        while (__hip_atomic_load(gen, __ATOMIC_RELAXED, __HIP_MEMORY_SCOPE_AGENT) == g)
          __builtin_amdgcn_s_sleep(2);
      }
    } else {
      while (__hip_atomic_load(gen, __ATOMIC_RELAXED, __HIP_MEMORY_SCOPE_AGENT) == g)
        __builtin_amdgcn_s_sleep(2);
    }
    __threadfence();
  }
  __syncthreads();
}

// ---------------------------------------------------------------- persistent GRU recurrence
// 256 blocks (1/CU), 256 threads. Block (mh = bid&3, sb = bid>>2):
//   phase1 tile: rows mh*32..+31, cols sb*32..+31 of [128 x 2048] z|r preacts, K=1536 (h then x)
//   phase2 tile: rows mh*32..+31, cols sb*16..+15 of [128 x 1024] h_tilde preacts, K=1024 (r*h)
// Waves: (mt = wv&1) m-tile, (kh = wv>>1) k-half; LDS reduce joins k-halves.
// Weight slabs live in LDS for all 512 steps (rows padded +16B => conflict-free b128 reads).
__global__ __launch_bounds__(256) void k_gru(
    const bf16* __restrict__ Wzr, const bf16* __restrict__ Whr,
    const bf16* __restrict__ xb,
    const float* __restrict__ bz, const float* __restrict__ br,
    float* __restrict__ out, float* __restrict__ h32,
    bf16* __restrict__ hb, bf16* __restrict__ rhb, float* __restrict__ zbuf,
    unsigned* __restrict__ bar)
{
  extern __shared__ char smem[];
  char* lds1 = smem;            // Wzr slab: 32 rows * 3088 B
  char* lds2 = smem + 98816;    // Whr slab: 16 rows * 2064 B
  char* scr  = smem + 131840;   // 4 KiB k-split reduce scratch

  const int bid = blockIdx.x;
  const int tid = threadIdx.x;
  const int lane = tid & 63, wv = tid >> 6;
  const int l15 = lane & 15, q = lane >> 4;
  const int mh = bid & 3;
  const int sb = bid >> 2;          // 0..63
  const int mt = wv & 1, kh = wv >> 1;

  // stage weight slabs once (padded rows)
  for (int i = 0; i < 24; ++i) {
    int ci = tid + i*256;                       // 6144 chunks of 16B
    int r = ci / 192, co = (ci % 192)*16;
    *(uint4*)(lds1 + r*3088 + co) = *(const uint4*)((const char*)Wzr + (size_t)(sb*32 + r)*3072 + co);
  }
  for (int i = 0; i < 8; ++i) {
    int ci = tid + i*256;                       // 2048 chunks
    int r = ci >> 7, co = (ci & 127)*16;
    *(uint4*)(lds2 + r*2064 + co) = *(const uint4*)((const char*)Whr + (size_t)(sb*16 + r)*2048 + co);
  }
  __syncthreads();

  const int arow = mh*32 + mt*16 + l15;         // A-row this lane loads (both phases)
  const bf16* hrow = hb  + (size_t)arow*HH;
  const bf16* rrow = rhb + (size_t)arow*HH;

  for (int t = 0; t < LT; ++t) {
    // ---------------- phase 1: z,r preacts ----------------
    {
      f32x4 acc[2] = {};
      const bf16* xrow = xb + ((size_t)(t*BB + arow))*DD;
      #pragma unroll 4
      for (int kk = 0; kk < 24; ++kk) {
        int k = kh*768 + kk*32;
        bf16x8 a = (k < HH) ? *(const bf16x8*)(hrow + k + 8*q)
                            : *(const bf16x8*)(xrow + (k - HH) + 8*q);
        #pragma unroll
        for (int nt = 0; nt < 2; ++nt) {
          bf16x8 b = *(const bf16x8*)(lds1 + (nt*16 + l15)*3088 + k*2 + 16*q);
          acc[nt] = __builtin_amdgcn_mfma_f32_16x16x32_bf16(a, b, acc[nt], 0, 0, 0);
        }
      }
      if (kh == 1) {
        *(f32x4*)(scr + (mt*2+0)*1024 + lane*16) = acc[0];
        *(f32x4*)(scr + (mt*2+1)*1024 + lane*16) = acc[1];
      }
      __syncthreads();
      if (kh == 0) {
        acc[0] += *(const f32x4*)(scr + (mt*2+0)*1024 + lane*16);
        acc[1] += *(const f32x4*)(scr + (mt*2+1)*1024 + lane*16);
        int c0 = sb*32;
        #pragma unroll
        for (int nt = 0; nt < 2; ++nt) {
          int c = c0 + nt*16 + l15;
          float bias = (c < HH) ? bz[c] : br[c - HH];
          #pragma unroll
          for (int e = 0; e < 4; ++e) {
            int m = mh*32 + mt*16 + 4*q + e;
            float g = 1.f/(1.f + __expf(-(acc[nt][e] + bias)));
            if (c < HH) {
              zbuf[m*HH + c] = g;
            } else {
              int cr = c - HH;
              rhb[(size_t)m*HH + cr] = (bf16)(g * h32[m*HH + cr]);
            }
          }
        }
      }
    }
    grid_barrier(bar, bid);
    // ---------------- phase 2: h_tilde + combine ----------------
    {
      f32x4 acc = {};
      #pragma unroll 4
      for (int kk = 0; kk < 16; ++kk) {
        int k = kh*512 + kk*32;
        bf16x8 a = *(const bf16x8*)(rrow + k + 8*q);
        bf16x8 b = *(const bf16x8*)(lds2 + l15*2064 + k*2 + 16*q);
        acc = __builtin_amdgcn_mfma_f32_16x16x32_bf16(a, b, acc, 0, 0, 0);
      }
      if (kh == 1) *(f32x4*)(scr + mt*1024 + lane*16) = acc;
      __syncthreads();
      if (kh == 0) {
        acc += *(const f32x4*)(scr + mt*1024 + lane*16);
        int j = sb*16 + l15;
        #pragma unroll
        for (int e = 0; e < 4; ++e) {
          int m = mh*32 + mt*16 + 4*q + e;
          int idx = m*HH + j;
          size_t oidx = (size_t)t*(BB*HH) + idx;
          float pre = acc[e] + out[oidx];        // out[t] holds Xh (+b_h) until overwritten
          float ht  = tanhf(pre);
          float z = zbuf[idx], h = h32[idx];
          float hn = h + z*(ht - h);
          out[oidx] = hn;
          h32[idx] = hn;
          hb[idx]  = (bf16)hn;
        }
      }
    }
    grid_barrier(bar, bid);
  }
}

// ---------------------------------------------------------------- launch
extern "C" void kernel_launch(void* const* d_in, const int* in_sizes, int n_in,
                              void* d_out, int out_size, void* d_ws, size_t ws_size,
                              hipStream_t stream) {
  const float* x  = (const float*)d_in[0];
  const float* h0 = (const float*)d_in[1];
  const float* Wz = (const float*)d_in[2];
  const float* bz = (const float*)d_in[3];
  const float* Wr = (const float*)d_in[4];
  const float* br = (const float*)d_in[5];
  const float* Wh = (const float*)d_in[6];
  const float* bh = (const float*)d_in[7];
  float* out = (float*)d_out;
  char* ws = (char*)d_ws;
  if (ws_size < (size_t)WS_NEED) return;   // would show as absmax failure -> ws too small

  bf16*  wzr  = (bf16*) (ws + O_WZR);
  bf16*  whr  = (bf16*) (ws + O_WHR);
  bf16*  wxh  = (bf16*) (ws + O_WXH);
  bf16*  xbb  = (bf16*) (ws + O_XB);
  float* h32  = (float*)(ws + O_H32);
  bf16*  hb   = (bf16*) (ws + O_HB);
  bf16*  rhb  = (bf16*) (ws + O_RHB);
  float* zbuf = (float*)(ws + O_ZB);
  unsigned* bar = (unsigned*)(ws + O_BAR);

  hipMemsetAsync(bar, 0, 4096, stream);                       // barrier state must be 0 each call
  k_cvt<<<16384, 256, 0, stream>>>(x, xbb, MT*DD/8);          // x -> bf16
  k_cvt<<<768, 256, 0, stream>>>(Wz, wzr, HH*HD/8);           // W_z full rows
  k_cvt<<<768, 256, 0, stream>>>(Wr, wzr + (size_t)HH*HD, HH*HD/8); // W_r full rows
  k_split_wh<<<768, 256, 0, stream>>>(Wh, whr, wxh);          // W_h split h/x parts
  k_init_h<<<128, 256, 0, stream>>>(h0, h32, hb);
  k_gemm_xh<<<4096, 256, 0, stream>>>(xbb, wxh, bh, out);     // out[t] <- Xh(t) + b_h

  hipFuncSetAttribute((const void*)k_gru, hipFuncAttributeMaxDynamicSharedMemorySize, 135936);
  k_gru<<<256, 256, 135936, stream>>>(wzr, whr, xbb, bz, br, out, h32, hb, rhb, zbuf, bar);
}

// Round 2
// 21978.802 us; speedup vs baseline: 1.0469x; 1.0469x over previous
//
#include <hip/hip_runtime.h>
#include <cstdint>
#include <cstddef>

// ---------------------------------------------------------------- sizes
#define LT 512
#define BB 128
#define DD 512
#define HH 1024
#define HD 1536
#define MT (LT*BB)   // 65536

typedef __bf16 bf16;
typedef __bf16 bf16x8 __attribute__((ext_vector_type(8)));
typedef __bf16 bf16x4 __attribute__((ext_vector_type(4)));
typedef float  f32x4  __attribute__((ext_vector_type(4)));

// ---------------------------------------------------------------- ws layout (bytes)
#define O_WZR 0u                 // bf16 [2048][1536]  rows 0..1023 = W_z, 1024.. = W_r
#define O_WHR 6291456u           // bf16 [1024][1024]  W_h[:, :H]
#define O_WXH 8388608u           // bf16 [1024][512]   W_h[:, H:]
#define O_XB  9437184u           // bf16 [65536][512]  x cast to bf16
#define O_H32 76546048u          // f32  [128][1024]   h state (write-through coherent)
#define O_HB  77070336u          // bf16 [128][1024]   h rounded (write-through coherent)
#define O_RHB 77332480u          // bf16 [128][1024]   r*h rounded (write-through coherent)
#define O_ZB  77594624u          // f32  [128][1024]   z gate (write-through coherent)
#define O_BAR 78118912u          // 4 groups x 4KB barrier pages
#define WS_NEED 78135296u

// ---------------------------------------------------------------- coherent store helpers
// Write-through to the coherence point (Infinity Cache): no wbl2 fences needed.
__device__ __forceinline__ void st_wt_f32(float* p, float v) {
  asm volatile("global_store_dword %0, %1, off sc0 sc1" :: "v"(p), "v"(v) : "memory");
}
__device__ __forceinline__ void st_wt_u16(bf16* p, unsigned v) {
  asm volatile("global_store_short %0, %1, off sc0 sc1" :: "v"(p), "v"(v) : "memory");
}
__device__ __forceinline__ unsigned bf16_bits(float f) {
  bf16 b = (bf16)f;
  unsigned short u = __builtin_bit_cast(unsigned short, b);
  return (unsigned)u;
}

// ---------------------------------------------------------------- small prep kernels
__global__ void k_cvt(const float* __restrict__ s, bf16* __restrict__ d, int n8) {
  int i = blockIdx.x*256 + threadIdx.x;
  if (i >= n8) return;
  const float4* p = (const float4*)s + (size_t)i*2;
  float4 a = p[0], b = p[1];
  bf16x8 v = {(bf16)a.x,(bf16)a.y,(bf16)a.z,(bf16)a.w,(bf16)b.x,(bf16)b.y,(bf16)b.z,(bf16)b.w};
  *((bf16x8*)d + i) = v;
}

__global__ void k_split_wh(const float* __restrict__ Wh, bf16* __restrict__ whr, bf16* __restrict__ wxh) {
  int i = blockIdx.x*256 + threadIdx.x;
  if (i >= 1024*192) return;
  int row = i / 192, c8 = (i % 192)*8;
  const float4* p = (const float4*)(Wh + (size_t)row*HD + c8);
  float4 a = p[0], b = p[1];
  bf16x8 v = {(bf16)a.x,(bf16)a.y,(bf16)a.z,(bf16)a.w,(bf16)b.x,(bf16)b.y,(bf16)b.z,(bf16)b.w};
  bf16* dptr = (c8 < HH) ? (whr + (size_t)row*HH + c8) : (wxh + (size_t)row*DD + (c8 - HH));
  *(bf16x8*)dptr = v;
}

__global__ void k_init_h(const float* __restrict__ h0, float* __restrict__ h32, bf16* __restrict__ hb) {
  int i = blockIdx.x*256 + threadIdx.x;
  float4 a = ((const float4*)h0)[i];
  ((float4*)h32)[i] = a;
  bf16x4 v = {(bf16)a.x,(bf16)a.y,(bf16)a.z,(bf16)a.w};
  *((bf16x4*)hb + i) = v;
}

// ---------------------------------------------------------------- Xh GEMM: out = x @ Wxh^T + b_h
__global__ __launch_bounds__(256) void k_gemm_xh(
    const bf16* __restrict__ xb, const bf16* __restrict__ wxh,
    const float* __restrict__ bh, float* __restrict__ out)
{
  __shared__ char As[16384];
  __shared__ char Bs[16384];
  const int bid = blockIdx.x;
  const int nt8 = bid & 7, mtb = bid >> 3;
  const int tid = threadIdx.x;
  const int lane = tid & 63, wv = tid >> 6;
  const int l15 = lane & 15, q = lane >> 4;
  const int wm = wv >> 1, wn = wv & 1;
  f32x4 acc[4][4] = {};
  const char* Ab = (const char*)(xb + (size_t)mtb*128*DD);
  const char* Bb = (const char*)(wxh + (size_t)nt8*128*DD);
  const int crow = tid >> 3, ccb = (tid & 7)*16;
  const int cdst = crow*128 + (ccb ^ ((crow & 7) << 4));
  for (int kt = 0; kt < 8; ++kt) {
    __syncthreads();
    #pragma unroll
    for (int i = 0; i < 4; ++i) {
      *(uint4*)(As + cdst + i*4096) = *(const uint4*)(Ab + (size_t)(crow + i*32)*1024 + kt*128 + ccb);
      *(uint4*)(Bs + cdst + i*4096) = *(const uint4*)(Bb + (size_t)(crow + i*32)*1024 + kt*128 + ccb);
    }
    __syncthreads();
    #pragma unroll
    for (int ks = 0; ks < 2; ++ks) {
      bf16x8 af[4], bfr[4];
      #pragma unroll
      for (int m4 = 0; m4 < 4; ++m4) {
        int row = wm*64 + m4*16 + l15, cb = ks*64 + 16*q;
        af[m4] = *(const bf16x8*)(As + row*128 + (cb ^ ((row&7)<<4)));
      }
      #pragma unroll
      for (int n4 = 0; n4 < 4; ++n4) {
        int row = wn*64 + n4*16 + l15, cb = ks*64 + 16*q;
        bfr[n4] = *(const bf16x8*)(Bs + row*128 + (cb ^ ((row&7)<<4)));
      }
      #pragma unroll
      for (int m4 = 0; m4 < 4; ++m4)
        #pragma unroll
        for (int n4 = 0; n4 < 4; ++n4)
          acc[m4][n4] = __builtin_amdgcn_mfma_f32_16x16x32_bf16(af[m4], bfr[n4], acc[m4][n4], 0, 0, 0);
    }
  }
  const int jb = nt8*128 + wn*64;
  const size_t mb = (size_t)mtb*128 + wm*64;
  #pragma unroll
  for (int n4 = 0; n4 < 4; ++n4) {
    int j = jb + n4*16 + l15;
    float bias = bh[j];
    #pragma unroll
    for (int m4 = 0; m4 < 4; ++m4)
      #pragma unroll
      for (int e = 0; e < 4; ++e) {
        size_t m = mb + m4*16 + 4*q + e;
        out[m*HH + j] = acc[m4][n4][e] + bias;
      }
  }
}

// ---------------------------------------------------------------- group barrier
// Per-group (64 blocks) hierarchical sense-free barrier: MONOTONIC relaxed IF
// atomics (no resets -> no reset/arrival races), 8 leaves x 8 blocks, <=8
// pollers per release word. No release fences anywhere (shared data is
// write-through); acquire side = buffer_inv only (cheap, no writeback).
__device__ __forceinline__ void grid_barrier(unsigned* barg, int sb) {
  asm volatile("s_waitcnt vmcnt(0)" ::: "memory");   // my wave's WT stores are at IF
  __syncthreads();                                   // all waves drained + arrived
  if (threadIdx.x == 0) {
    unsigned* leaf = barg + (sb & 7)*32;
    unsigned* root = barg + 8*32;
    unsigned* lgen = barg + (9 + (sb & 7))*32;
    unsigned g = __hip_atomic_load(lgen, __ATOMIC_RELAXED, __HIP_MEMORY_SCOPE_AGENT);
    unsigned lold = __hip_atomic_fetch_add(leaf, 1u, __ATOMIC_RELAXED, __HIP_MEMORY_SCOPE_AGENT);
    if ((lold & 7u) == 7u) {
      unsigned rold = __hip_atomic_fetch_add(root, 1u, __ATOMIC_RELAXED, __HIP_MEMORY_SCOPE_AGENT);
      if ((rold & 7u) == 7u) {
        #pragma unroll
        for (int i = 0; i < 8; ++i)
          __hip_atomic_store(barg + (9+i)*32, g + 1u, __ATOMIC_RELAXED, __HIP_MEMORY_SCOPE_AGENT);
      } else {
        do { __builtin_amdgcn_s_sleep(1); }
        while (__hip_atomic_load(lgen, __ATOMIC_RELAXED, __HIP_MEMORY_SCOPE_AGENT) == g);
      }
    } else {
      do { __builtin_amdgcn_s_sleep(1); }
      while (__hip_atomic_load(lgen, __ATOMIC_RELAXED, __HIP_MEMORY_SCOPE_AGENT) == g);
    }
  }
  __syncthreads();
  __builtin_amdgcn_fence(__ATOMIC_ACQUIRE, "agent"); // waitcnt + buffer_inv (no wbl2)
}

// ---------------------------------------------------------------- persistent GRU recurrence
// 256 blocks x 512 threads. group g = bid&3 owns batch rows [g*32, g*32+32) —
// groups are fully independent (separate barriers, may skew).
// Within a group: sb = bid>>2 in [0,64):
//   phase1: preact cols sb*32..+31 of [32 x 2048] z|r, K=1536 (h|x)
//   phase2: cols sb*16..+15 of [32 x 1024] h_tilde, K=1024 (r*h)
// 8 waves: mt = wv&1 (row half), kh = wv>>1 (K quarter); LDS reduce joins.
__global__ __launch_bounds__(512) void k_gru(
    const bf16* __restrict__ Wzr, const bf16* __restrict__ Whr,
    const bf16* __restrict__ xb,
    const float* __restrict__ bz, const float* __restrict__ br,
    float* __restrict__ out, float* __restrict__ h32,
    bf16* __restrict__ hb, bf16* __restrict__ rhb, float* __restrict__ zbuf,
    unsigned* __restrict__ bar)
{
  extern __shared__ char smem[];
  char* lds1 = smem;            // Wzr slab: 32 rows * 3088 B (16B pad -> 2-way-free LDS reads)
  char* lds2 = smem + 98816;    // Whr slab: 16 rows * 2064 B
  char* scr  = smem + 131840;   // 12 KiB k-split reduce scratch

  const int bid = blockIdx.x;
  const int tid = threadIdx.x;
  const int lane = tid & 63, wv = tid >> 6;
  const int l15 = lane & 15, q = lane >> 4;
  const int g  = bid & 3;
  const int sb = bid >> 2;          // 0..63
  const int mt = wv & 1, kh = wv >> 1;   // kh in 0..3
  unsigned* barg = bar + g*1024;

  // stage weight slabs once (padded rows)
  #pragma unroll
  for (int i = 0; i < 12; ++i) {
    int ci = tid + i*512;                       // 6144 chunks of 16B
    int r = ci / 192, co = (ci % 192)*16;
    *(uint4*)(lds1 + r*3088 + co) = *(const uint4*)((const char*)Wzr + (size_t)(sb*32 + r)*3072 + co);
  }
  #pragma unroll
  for (int i = 0; i < 4; ++i) {
    int ci = tid + i*512;                       // 2048 chunks
    int r = ci >> 7, co = (ci & 127)*16;
    *(uint4*)(lds2 + r*2064 + co) = *(const uint4*)((const char*)Whr + (size_t)(sb*16 + r)*2048 + co);
  }

  const int arow = g*32 + mt*16 + l15;          // A-row this lane loads (both phases)
  const bf16* hrow = hb  + (size_t)arow*HH;
  const bf16* rrow = rhb + (size_t)arow*HH;

  float bias[2];
  #pragma unroll
  for (int nt = 0; nt < 2; ++nt) {              // hoisted: per-lane gate bias
    int c = sb*32 + nt*16 + l15;
    bias[nt] = (c < HH) ? bz[c] : br[c - HH];
  }
  __syncthreads();

  for (int t = 0; t < LT; ++t) {
    // ---------------- phase 1: z,r preacts ----------------
    {
      f32x4 acc0 = {}, acc1 = {};
      const bf16* xrow = xb + ((size_t)(t*BB + arow))*DD;
      #pragma unroll
      for (int kk = 0; kk < 12; ++kk) {
        int k = kh*384 + kk*32;
        bf16x8 a = (k < HH) ? *(const bf16x8*)(hrow + k + 8*q)
                            : *(const bf16x8*)(xrow + (k - HH) + 8*q);
        bf16x8 b0 = *(const bf16x8*)(lds1 + l15*3088      + k*2 + 16*q);
        bf16x8 b1 = *(const bf16x8*)(lds1 + (16+l15)*3088 + k*2 + 16*q);
        acc0 = __builtin_amdgcn_mfma_f32_16x16x32_bf16(a, b0, acc0, 0, 0, 0);
        acc1 = __builtin_amdgcn_mfma_f32_16x16x32_bf16(a, b1, acc1, 0, 0, 0);
      }
      if (kh) {
        int s = ((kh-1)*2 + mt)*2;
        *(f32x4*)(scr + (s+0)*1024 + lane*16) = acc0;
        *(f32x4*)(scr + (s+1)*1024 + lane*16) = acc1;
      }
      __syncthreads();
      if (kh == 0) {
        #pragma unroll
        for (int k2 = 0; k2 < 3; ++k2) {
          int s = (k2*2 + mt)*2;
          acc0 += *(const f32x4*)(scr + (s+0)*1024 + lane*16);
          acc1 += *(const f32x4*)(scr + (s+1)*1024 + lane*16);
        }
        #pragma unroll
        for (int nt = 0; nt < 2; ++nt) {
          f32x4 ac = nt ? acc1 : acc0;
          int c = sb*32 + nt*16 + l15;
          #pragma unroll
          for (int e = 0; e < 4; ++e) {
            int m = g*32 + mt*16 + 4*q + e;     // C/D: col=lane&15, row=4*(lane>>4)+e
            float gate = 1.f/(1.f + __expf(-(ac[e] + bias[nt])));
            if (c < HH) {
              st_wt_f32(zbuf + (size_t)m*HH + c, gate);
            } else {
              int cr = c - HH;
              float rh = gate * h32[(size_t)m*HH + cr];
              st_wt_u16(rhb + (size_t)m*HH + cr, bf16_bits(rh));
            }
          }
        }
      }
    }
    grid_barrier(barg, sb);
    // ---------------- phase 2: h_tilde + combine ----------------
    {
      f32x4 acc = {};
      #pragma unroll
      for (int kk = 0; kk < 8; ++kk) {
        int k = kh*256 + kk*32;
        bf16x8 a = *(const bf16x8*)(rrow + k + 8*q);
        bf16x8 b = *(const bf16x8*)(lds2 + l15*2064 + k*2 + 16*q);
        acc = __builtin_amdgcn_mfma_f32_16x16x32_bf16(a, b, acc, 0, 0, 0);
      }
      if (kh) *(f32x4*)(scr + ((kh-1)*2 + mt)*1024 + lane*16) = acc;
      __syncthreads();
      if (kh == 0) {
        #pragma unroll
        for (int k2 = 0; k2 < 3; ++k2)
          acc += *(const f32x4*)(scr + (k2*2 + mt)*1024 + lane*16);
        int j = sb*16 + l15;
        #pragma unroll
        for (int e = 0; e < 4; ++e) {
          int m = g*32 + mt*16 + 4*q + e;
          size_t idx = (size_t)m*HH + j;
          size_t oidx = (size_t)t*(BB*HH) + idx;
          float pre = acc[e] + out[oidx];        // out[t] holds Xh+b_h until overwritten
          float ht  = tanhf(pre);
          float z = zbuf[idx], h = h32[idx];
          float hn = h + z*(ht - h);
          out[oidx] = hn;                        // plain store (nobody re-reads mid-kernel)
          st_wt_f32(h32 + idx, hn);
          st_wt_u16(hb + idx, bf16_bits(hn));
        }
      }
    }
    grid_barrier(barg, sb);
  }
}

// ---------------------------------------------------------------- launch
extern "C" void kernel_launch(void* const* d_in, const int* in_sizes, int n_in,
                              void* d_out, int out_size, void* d_ws, size_t ws_size,
                              hipStream_t stream) {
  const float* x  = (const float*)d_in[0];
  const float* h0 = (const float*)d_in[1];
  const float* Wz = (const float*)d_in[2];
  const float* bz = (const float*)d_in[3];
  const float* Wr = (const float*)d_in[4];
  const float* br = (const float*)d_in[5];
  const float* Wh = (const float*)d_in[6];
  const float* bh = (const float*)d_in[7];
  float* out = (float*)d_out;
  char* ws = (char*)d_ws;
  if (ws_size < (size_t)WS_NEED) return;

  bf16*  wzr  = (bf16*) (ws + O_WZR);
  bf16*  whr  = (bf16*) (ws + O_WHR);
  bf16*  wxh  = (bf16*) (ws + O_WXH);
  bf16*  xbb  = (bf16*) (ws + O_XB);
  float* h32  = (float*)(ws + O_H32);
  bf16*  hb   = (bf16*) (ws + O_HB);
  bf16*  rhb  = (bf16*) (ws + O_RHB);
  float* zbuf = (float*)(ws + O_ZB);
  unsigned* bar = (unsigned*)(ws + O_BAR);

  hipMemsetAsync(bar, 0, 16384, stream);                      // monotonic counters start at 0
  k_cvt<<<16384, 256, 0, stream>>>(x, xbb, MT*DD/8);
  k_cvt<<<768, 256, 0, stream>>>(Wz, wzr, HH*HD/8);
  k_cvt<<<768, 256, 0, stream>>>(Wr, wzr + (size_t)HH*HD, HH*HD/8);
  k_split_wh<<<768, 256, 0, stream>>>(Wh, whr, wxh);
  k_init_h<<<128, 256, 0, stream>>>(h0, h32, hb);
  k_gemm_xh<<<4096, 256, 0, stream>>>(xbb, wxh, bh, out);

  hipFuncSetAttribute((const void*)k_gru, hipFuncAttributeMaxDynamicSharedMemorySize, 144128);
  k_gru<<<256, 512, 144128, stream>>>(wzr, whr, xbb, bz, br, out, h32, hb, rhb, zbuf, bar);
}

// Round 3
// 6392.168 us; speedup vs baseline: 3.5997x; 3.4384x over previous
//
#include <hip/hip_runtime.h>
#include <cstdint>
#include <cstddef>

// ---------------------------------------------------------------- sizes
#define LT 512
#define BB 128
#define DD 512
#define HH 1024
#define HD 1536
#define MT (LT*BB)   // 65536

typedef __bf16 bf16;
typedef __bf16 bf16x8 __attribute__((ext_vector_type(8)));
typedef __bf16 bf16x4 __attribute__((ext_vector_type(4)));
typedef float  f32x4  __attribute__((ext_vector_type(4)));

// ---------------------------------------------------------------- ws layout (bytes)
#define O_WZR 0u                 // bf16 [2048][1536]  rows 0..1023 = W_z, 1024.. = W_r
#define O_WHR 6291456u           // bf16 [1024][1024]  W_h[:, :H]
#define O_WXH 8388608u           // bf16 [1024][512]   W_h[:, H:]
#define O_XB  9437184u           // bf16 [65536][512]  x cast to bf16
#define O_H32 76546048u          // f32  [128][1024]   h state (WT coherent, read via sc1)
#define O_HB  77070336u          // bf16 [128][1024]   h rounded (WT coherent)
#define O_RHB 77332480u          // bf16 [128][1024]   r*h rounded (WT coherent)
#define O_ZB  77594624u          // f32  [128][1024]   z gate (WT coherent)
#define O_BAR 78118912u          // 4 groups x 4KB barrier pages
#define WS_NEED 78135296u

// ---------------------------------------------------------------- coherent access helpers
// Write-through / read-through the coherence point (IF). NO cache fences anywhere.
__device__ __forceinline__ void st_wt_f32(float* p, float v) {
  asm volatile("global_store_dword %0, %1, off sc0 sc1" :: "v"(p), "v"(v) : "memory");
}
__device__ __forceinline__ void st_wt_u16(bf16* p, unsigned v) {
  asm volatile("global_store_short %0, %1, off sc0 sc1" :: "v"(p), "v"(v) : "memory");
}
__device__ __forceinline__ f32x4 ld_cg16(const void* p) {   // 16B load, bypass L1+L2
  f32x4 r;
  asm volatile("global_load_dwordx4 %0, %1, off sc0 sc1" : "=v"(r) : "v"(p) : "memory");
  return r;
}
__device__ __forceinline__ float ld_cg4(const void* p) {    // 4B load, bypass L1+L2
  float r;
  asm volatile("global_load_dword %0, %1, off sc0 sc1" : "=v"(r) : "v"(p) : "memory");
  return r;
}
#define WAIT_VM0() asm volatile("s_waitcnt vmcnt(0)" ::: "memory")
__device__ __forceinline__ unsigned bf16_bits(float f) {
  bf16 b = (bf16)f;
  unsigned short u = __builtin_bit_cast(unsigned short, b);
  return (unsigned)u;
}

// ---------------------------------------------------------------- small prep kernels
__global__ void k_cvt(const float* __restrict__ s, bf16* __restrict__ d, int n8) {
  int i = blockIdx.x*256 + threadIdx.x;
  if (i >= n8) return;
  const float4* p = (const float4*)s + (size_t)i*2;
  float4 a = p[0], b = p[1];
  bf16x8 v = {(bf16)a.x,(bf16)a.y,(bf16)a.z,(bf16)a.w,(bf16)b.x,(bf16)b.y,(bf16)b.z,(bf16)b.w};
  *((bf16x8*)d + i) = v;
}

__global__ void k_split_wh(const float* __restrict__ Wh, bf16* __restrict__ whr, bf16* __restrict__ wxh) {
  int i = blockIdx.x*256 + threadIdx.x;
  if (i >= 1024*192) return;
  int row = i / 192, c8 = (i % 192)*8;
  const float4* p = (const float4*)(Wh + (size_t)row*HD + c8);
  float4 a = p[0], b = p[1];
  bf16x8 v = {(bf16)a.x,(bf16)a.y,(bf16)a.z,(bf16)a.w,(bf16)b.x,(bf16)b.y,(bf16)b.z,(bf16)b.w};
  bf16* dptr = (c8 < HH) ? (whr + (size_t)row*HH + c8) : (wxh + (size_t)row*DD + (c8 - HH));
  *(bf16x8*)dptr = v;
}

__global__ void k_init_h(const float* __restrict__ h0, float* __restrict__ h32, bf16* __restrict__ hb) {
  int i = blockIdx.x*256 + threadIdx.x;
  float4 a = ((const float4*)h0)[i];
  ((float4*)h32)[i] = a;
  bf16x4 v = {(bf16)a.x,(bf16)a.y,(bf16)a.z,(bf16)a.w};
  *((bf16x4*)hb + i) = v;
}

// ---------------------------------------------------------------- Xh GEMM: out = x @ Wxh^T + b_h
__global__ __launch_bounds__(256) void k_gemm_xh(
    const bf16* __restrict__ xb, const bf16* __restrict__ wxh,
    const float* __restrict__ bh, float* __restrict__ out)
{
  __shared__ char As[16384];
  __shared__ char Bs[16384];
  const int bid = blockIdx.x;
  const int nt8 = bid & 7, mtb = bid >> 3;
  const int tid = threadIdx.x;
  const int lane = tid & 63, wv = tid >> 6;
  const int l15 = lane & 15, q = lane >> 4;
  const int wm = wv >> 1, wn = wv & 1;
  f32x4 acc[4][4] = {};
  const char* Ab = (const char*)(xb + (size_t)mtb*128*DD);
  const char* Bb = (const char*)(wxh + (size_t)nt8*128*DD);
  const int crow = tid >> 3, ccb = (tid & 7)*16;
  const int cdst = crow*128 + (ccb ^ ((crow & 7) << 4));
  for (int kt = 0; kt < 8; ++kt) {
    __syncthreads();
    #pragma unroll
    for (int i = 0; i < 4; ++i) {
      *(uint4*)(As + cdst + i*4096) = *(const uint4*)(Ab + (size_t)(crow + i*32)*1024 + kt*128 + ccb);
      *(uint4*)(Bs + cdst + i*4096) = *(const uint4*)(Bb + (size_t)(crow + i*32)*1024 + kt*128 + ccb);
    }
    __syncthreads();
    #pragma unroll
    for (int ks = 0; ks < 2; ++ks) {
      bf16x8 af[4], bfr[4];
      #pragma unroll
      for (int m4 = 0; m4 < 4; ++m4) {
        int row = wm*64 + m4*16 + l15, cb = ks*64 + 16*q;
        af[m4] = *(const bf16x8*)(As + row*128 + (cb ^ ((row&7)<<4)));
      }
      #pragma unroll
      for (int n4 = 0; n4 < 4; ++n4) {
        int row = wn*64 + n4*16 + l15, cb = ks*64 + 16*q;
        bfr[n4] = *(const bf16x8*)(Bs + row*128 + (cb ^ ((row&7)<<4)));
      }
      #pragma unroll
      for (int m4 = 0; m4 < 4; ++m4)
        #pragma unroll
        for (int n4 = 0; n4 < 4; ++n4)
          acc[m4][n4] = __builtin_amdgcn_mfma_f32_16x16x32_bf16(af[m4], bfr[n4], acc[m4][n4], 0, 0, 0);
    }
  }
  const int jb = nt8*128 + wn*64;
  const size_t mb = (size_t)mtb*128 + wm*64;
  #pragma unroll
  for (int n4 = 0; n4 < 4; ++n4) {
    int j = jb + n4*16 + l15;
    float bias = bh[j];
    #pragma unroll
    for (int m4 = 0; m4 < 4; ++m4)
      #pragma unroll
      for (int e = 0; e < 4; ++e) {
        size_t m = mb + m4*16 + 4*q + e;
        out[m*HH + j] = acc[m4][n4][e] + bias;
      }
  }
}

// ---------------------------------------------------------------- group barrier
// Monotonic relaxed agent atomics ONLY — no fences, no cache maintenance.
// Causality lives at the IF: producers' WT stores are vmcnt-drained by the
// entry __syncthreads before the arrival add; consumers read shared data
// through sc0 sc1 loads (L1/L2 bypass), so no invalidation is ever needed.
__device__ __forceinline__ void grid_barrier(unsigned* barg, int sb) {
  __syncthreads();                                   // drains vmcnt -> WT data at IF
  if (threadIdx.x == 0) {
    unsigned* leaf = barg + (sb & 7)*32;
    unsigned* root = barg + 8*32;
    unsigned* lgen = barg + (9 + (sb & 7))*32;
    unsigned g = __hip_atomic_load(lgen, __ATOMIC_RELAXED, __HIP_MEMORY_SCOPE_AGENT);
    unsigned lold = __hip_atomic_fetch_add(leaf, 1u, __ATOMIC_RELAXED, __HIP_MEMORY_SCOPE_AGENT);
    if ((lold & 7u) == 7u) {
      unsigned rold = __hip_atomic_fetch_add(root, 1u, __ATOMIC_RELAXED, __HIP_MEMORY_SCOPE_AGENT);
      if ((rold & 7u) == 7u) {
        #pragma unroll
        for (int i = 0; i < 8; ++i)
          __hip_atomic_store(barg + (9+i)*32, g + 1u, __ATOMIC_RELAXED, __HIP_MEMORY_SCOPE_AGENT);
      } else {
        do { __builtin_amdgcn_s_sleep(1); }
        while (__hip_atomic_load(lgen, __ATOMIC_RELAXED, __HIP_MEMORY_SCOPE_AGENT) == g);
      }
    } else {
      do { __builtin_amdgcn_s_sleep(1); }
      while (__hip_atomic_load(lgen, __ATOMIC_RELAXED, __HIP_MEMORY_SCOPE_AGENT) == g);
    }
  }
  __syncthreads();
}

// ---------------------------------------------------------------- persistent GRU recurrence
// 256 blocks x 512 threads. group g = bid&3 owns batch rows [g*32, g*32+32).
// sb = bid>>2 in [0,64): sb<32 -> z cols sb*32..+31 ; sb>=32 -> r cols (sb*32-1024)..+31.
// phase2: h_tilde cols sb*16..+15, K=1024 over r*h.
// 8 waves: mt = wv&1 (row half), kh = wv>>1 (K quarter); LDS reduce joins.
__global__ __launch_bounds__(512) void k_gru(
    const bf16* __restrict__ Wzr, const bf16* __restrict__ Whr,
    const bf16* __restrict__ xb,
    const float* __restrict__ bz, const float* __restrict__ br,
    float* __restrict__ out, float* __restrict__ h32,
    bf16* __restrict__ hb, bf16* __restrict__ rhb, float* __restrict__ zbuf,
    unsigned* __restrict__ bar)
{
  extern __shared__ char smem[];
  char* lds1 = smem;            // Wzr slab: 32 rows * 3088 B
  char* lds2 = smem + 98816;    // Whr slab: 16 rows * 2064 B
  char* scr  = smem + 131840;   // 12 KiB k-split reduce scratch

  const int bid = blockIdx.x;
  const int tid = threadIdx.x;
  const int lane = tid & 63, wv = tid >> 6;
  const int l15 = lane & 15, q = lane >> 4;
  const int g  = bid & 3;
  const int sb = bid >> 2;               // 0..63
  const int mt = wv & 1, kh = wv >> 1;   // kh in 0..3
  unsigned* barg = bar + g*1024;

  // stage weight slabs once (padded rows)
  #pragma unroll
  for (int i = 0; i < 12; ++i) {
    int ci = tid + i*512;
    int r = ci / 192, co = (ci % 192)*16;
    *(uint4*)(lds1 + r*3088 + co) = *(const uint4*)((const char*)Wzr + (size_t)(sb*32 + r)*3072 + co);
  }
  #pragma unroll
  for (int i = 0; i < 4; ++i) {
    int ci = tid + i*512;
    int r = ci >> 7, co = (ci & 127)*16;
    *(uint4*)(lds2 + r*2064 + co) = *(const uint4*)((const char*)Whr + (size_t)(sb*16 + r)*2048 + co);
  }

  const int arow = g*32 + mt*16 + l15;   // A-row this lane loads (both phases)
  const bf16* hrow = hb  + (size_t)arow*HH;
  const bf16* rrow = rhb + (size_t)arow*HH;

  float bias[2];
  #pragma unroll
  for (int nt = 0; nt < 2; ++nt) {       // block is all-z (sb<32) or all-r (sb>=32)
    int c = sb*32 + nt*16 + l15;
    bias[nt] = (sb < 32) ? bz[c] : br[c - HH];
  }

  // phase-2 combine lanes own fixed (m, j) forever -> keep h in registers.
  float hreg[4];
  const int jown = sb*16 + l15;
  #pragma unroll
  for (int e = 0; e < 4; ++e) {
    int m = g*32 + mt*16 + 4*q + e;
    hreg[e] = h32[(size_t)m*HH + jown];  // plain load: fresh at kernel start
  }
  __syncthreads();

  for (int t = 0; t < LT; ++t) {
    // ---------------- phase 1: z or r preacts ----------------
    {
      f32x4 abuf[12];
      const bf16* xrow = xb + ((size_t)(t*BB + arow))*DD;
      #pragma unroll
      for (int kk = 0; kk < 12; ++kk) {
        int k = kh*384 + kk*32;
        if (k < HH) abuf[kk] = ld_cg16(hrow + k + 8*q);                 // coherent (IF)
        else        abuf[kk] = *(const f32x4*)(xrow + (k - HH) + 8*q);  // plain cached
      }
      WAIT_VM0();
      f32x4 acc0 = {}, acc1 = {};
      #pragma unroll
      for (int kk = 0; kk < 12; ++kk) {
        int k = kh*384 + kk*32;
        bf16x8 a  = __builtin_bit_cast(bf16x8, abuf[kk]);
        bf16x8 b0 = *(const bf16x8*)(lds1 + l15*3088      + k*2 + 16*q);
        bf16x8 b1 = *(const bf16x8*)(lds1 + (16+l15)*3088 + k*2 + 16*q);
        acc0 = __builtin_amdgcn_mfma_f32_16x16x32_bf16(a, b0, acc0, 0, 0, 0);
        acc1 = __builtin_amdgcn_mfma_f32_16x16x32_bf16(a, b1, acc1, 0, 0, 0);
      }
      if (kh) {
        int s = ((kh-1)*2 + mt)*2;
        *(f32x4*)(scr + (s+0)*1024 + lane*16) = acc0;
        *(f32x4*)(scr + (s+1)*1024 + lane*16) = acc1;
      }
      __syncthreads();
      if (kh == 0) {
        #pragma unroll
        for (int k2 = 0; k2 < 3; ++k2) {
          int s = (k2*2 + mt)*2;
          acc0 += *(const f32x4*)(scr + (s+0)*1024 + lane*16);
          acc1 += *(const f32x4*)(scr + (s+1)*1024 + lane*16);
        }
        if (sb < 32) {                      // ---- z block ----
          #pragma unroll
          for (int nt = 0; nt < 2; ++nt) {
            f32x4 ac = nt ? acc1 : acc0;
            int c = sb*32 + nt*16 + l15;
            #pragma unroll
            for (int e = 0; e < 4; ++e) {
              int m = g*32 + mt*16 + 4*q + e;
              float gate = 1.f/(1.f + __expf(-(ac[e] + bias[nt])));
              st_wt_f32(zbuf + (size_t)m*HH + c, gate);
            }
          }
        } else {                            // ---- r block: needs cross-block h ----
          float hv[2][4];
          #pragma unroll
          for (int nt = 0; nt < 2; ++nt) {
            int cr = sb*32 - HH + nt*16 + l15;
            #pragma unroll
            for (int e = 0; e < 4; ++e) {
              int m = g*32 + mt*16 + 4*q + e;
              hv[nt][e] = ld_cg4(h32 + (size_t)m*HH + cr);
            }
          }
          WAIT_VM0();
          #pragma unroll
          for (int nt = 0; nt < 2; ++nt) {
            f32x4 ac = nt ? acc1 : acc0;
            int cr = sb*32 - HH + nt*16 + l15;
            #pragma unroll
            for (int e = 0; e < 4; ++e) {
              int m = g*32 + mt*16 + 4*q + e;
              float gate = 1.f/(1.f + __expf(-(ac[e] + bias[nt])));
              st_wt_u16(rhb + (size_t)m*HH + cr, bf16_bits(gate * hv[nt][e]));
            }
          }
        }
      }
    }
    grid_barrier(barg, sb);
    // ---------------- phase 2: h_tilde + combine ----------------
    {
      f32x4 rbuf[8];
      #pragma unroll
      for (int kk = 0; kk < 8; ++kk) {
        int k = kh*256 + kk*32;
        rbuf[kk] = ld_cg16(rrow + k + 8*q);                             // coherent (IF)
      }
      WAIT_VM0();
      f32x4 acc = {};
      #pragma unroll
      for (int kk = 0; kk < 8; ++kk) {
        int k = kh*256 + kk*32;
        bf16x8 a = __builtin_bit_cast(bf16x8, rbuf[kk]);
        bf16x8 b = *(const bf16x8*)(lds2 + l15*2064 + k*2 + 16*q);
        acc = __builtin_amdgcn_mfma_f32_16x16x32_bf16(a, b, acc, 0, 0, 0);
      }
      if (kh) *(f32x4*)(scr + ((kh-1)*2 + mt)*1024 + lane*16) = acc;
      __syncthreads();
      if (kh == 0) {
        #pragma unroll
        for (int k2 = 0; k2 < 3; ++k2)
          acc += *(const f32x4*)(scr + (k2*2 + mt)*1024 + lane*16);
        float zv[4];
        #pragma unroll
        for (int e = 0; e < 4; ++e) {       // z was written by a different block
          int m = g*32 + mt*16 + 4*q + e;
          zv[e] = ld_cg4(zbuf + (size_t)m*HH + jown);
        }
        WAIT_VM0();
        #pragma unroll
        for (int e = 0; e < 4; ++e) {
          int m = g*32 + mt*16 + 4*q + e;
          size_t idx = (size_t)m*HH + jown;
          size_t oidx = (size_t)t*(BB*HH) + idx;
          float pre = acc[e] + out[oidx];   // plain cached: out[t] holds Xh+b_h
          float ht  = tanhf(pre);
          float h = hreg[e];
          float hn = h + zv[e]*(ht - h);
          out[oidx] = hn;                   // plain store (block-private slot)
          hreg[e] = hn;
          st_wt_f32(h32 + idx, hn);         // for next step's r blocks
          st_wt_u16(hb + idx, bf16_bits(hn)); // for next step's phase-1 A loads
        }
      }
    }
    grid_barrier(barg, sb);
  }
}

// ---------------------------------------------------------------- launch
extern "C" void kernel_launch(void* const* d_in, const int* in_sizes, int n_in,
                              void* d_out, int out_size, void* d_ws, size_t ws_size,
                              hipStream_t stream) {
  const float* x  = (const float*)d_in[0];
  const float* h0 = (const float*)d_in[1];
  const float* Wz = (const float*)d_in[2];
  const float* bz = (const float*)d_in[3];
  const float* Wr = (const float*)d_in[4];
  const float* br = (const float*)d_in[5];
  const float* Wh = (const float*)d_in[6];
  const float* bh = (const float*)d_in[7];
  float* out = (float*)d_out;
  char* ws = (char*)d_ws;
  if (ws_size < (size_t)WS_NEED) return;

  bf16*  wzr  = (bf16*) (ws + O_WZR);
  bf16*  whr  = (bf16*) (ws + O_WHR);
  bf16*  wxh  = (bf16*) (ws + O_WXH);
  bf16*  xbb  = (bf16*) (ws + O_XB);
  float* h32  = (float*)(ws + O_H32);
  bf16*  hb   = (bf16*) (ws + O_HB);
  bf16*  rhb  = (bf16*) (ws + O_RHB);
  float* zbuf = (float*)(ws + O_ZB);
  unsigned* bar = (unsigned*)(ws + O_BAR);

  hipMemsetAsync(bar, 0, 16384, stream);
  k_cvt<<<16384, 256, 0, stream>>>(x, xbb, MT*DD/8);
  k_cvt<<<768, 256, 0, stream>>>(Wz, wzr, HH*HD/8);
  k_cvt<<<768, 256, 0, stream>>>(Wr, wzr + (size_t)HH*HD, HH*HD/8);
  k_split_wh<<<768, 256, 0, stream>>>(Wh, whr, wxh);
  k_init_h<<<128, 256, 0, stream>>>(h0, h32, hb);
  k_gemm_xh<<<4096, 256, 0, stream>>>(xbb, wxh, bh, out);

  hipFuncSetAttribute((const void*)k_gru, hipFuncAttributeMaxDynamicSharedMemorySize, 144128);
  k_gru<<<256, 512, 144128, stream>>>(wzr, whr, xbb, bz, br, out, h32, hb, rhb, zbuf, bar);
}